// Round 2
// baseline (548.600 us; speedup 1.0000x reference)
//
#include <hip/hip_runtime.h>

#pragma clang fp contract(off)

#define NBOX 8192
#define BLK  1024
#define EPT  8            // elements per thread (NBOX / BLK)
#define NBUCK 2048
#define IOU_THR 0.1f

typedef unsigned int u32;
typedef unsigned long long u64;

__global__ void zero_kernel(float4* __restrict__ o, int n4) {
    int i = blockIdx.x * blockDim.x + threadIdx.x;
    if (i < n4) { float4 z; z.x = z.y = z.z = z.w = 0.0f; o[i] = z; }
}

__global__ __launch_bounds__(BLK) void nms_kernel(const float* __restrict__ in,
                                                  float* __restrict__ out) {
    const int img = blockIdx.x;
    const float* __restrict__ p = in + (size_t)img * 5 * NBOX;
    float* __restrict__ o = out + (size_t)img * 5 * NBOX;
    const int t = threadIdx.x;
    const int lane = t & 63;
    const int wid = t >> 6;

    __shared__ u64 skey[NBOX];        // 64 KB
    __shared__ u32 sidx[NBOX];        // 32 KB
    __shared__ u32 hist[NBUCK];       // 8 KB (becomes final counts)
    __shared__ u32 bbase[NBUCK];      // 8 KB
    __shared__ u32 kom[NBOX / 32];    // 1 KB keep bitmask (original idx)
    __shared__ u32 pfx[NBOX / 32];    // 1 KB
    __shared__ float4 bx4[64];        // 1 KB batch boxes (x1,y1,x2,y2)
    __shared__ int wcnt[BLK / 64];

    // ---- init ----
    for (int i = t; i < NBUCK; i += BLK) hist[i] = 0;
    for (int i = t; i < NBOX / 32; i += BLK) kom[i] = 0;
    __syncthreads();

    // ---- pass 1: bucket + arrival order (uniform scores -> ~4/bucket) ----
    u32 mybkt[EPT], myarr[EPT], mykeyhi[EPT];
#pragma unroll
    for (int e = 0; e < EPT; e++) {
        int j = t + e * BLK;
        float s = p[4 * NBOX + j];
        u32 u = __float_as_uint(s);
        u32 ordb = u ^ (u32)(((int)u >> 31) | (int)0x80000000);  // ascending orderable
        mykeyhi[e] = ~ordb;                                      // ascending == score desc
        int vb = (int)(s * (float)NBUCK);
        vb = vb < 0 ? 0 : (vb > NBUCK - 1 ? NBUCK - 1 : vb);
        mybkt[e] = (u32)(NBUCK - 1 - vb);                        // bucket asc == score desc
        myarr[e] = atomicAdd(&hist[mybkt[e]], 1u);
    }
    __syncthreads();

    // ---- exclusive scan over hist (2 bins/thread) ----
    {
        u32 h0 = hist[2 * t], h1 = hist[2 * t + 1];
        int v = (int)(h0 + h1);
        int x = v;
        for (int d = 1; d < 64; d <<= 1) {
            int y = __shfl_up(x, d, 64);
            if (lane >= d) x += y;
        }
        if (lane == 63) wcnt[wid] = x;
        __syncthreads();
        int wb = 0;
        for (int i = 0; i < wid; i++) wb += wcnt[i];
        int excl = wb + x - v;
        bbase[2 * t] = (u32)excl;
        bbase[2 * t + 1] = (u32)excl + h0;
    }
    __syncthreads();

    // ---- scatter keys into bucket regions ----
#pragma unroll
    for (int e = 0; e < EPT; e++) {
        u32 pos = bbase[mybkt[e]] + myarr[e];
        skey[pos] = ((u64)mykeyhi[e] << 32) | (u32)(t + e * BLK);
    }
    __syncthreads();

    // ---- rank within bucket (independent reads, no dependent chains) ----
#pragma unroll
    for (int e = 0; e < EPT; e++) {
        u32 b = mybkt[e];
        u32 lo = bbase[b], hi2 = lo + hist[b];
        u64 me = ((u64)mykeyhi[e] << 32) | (u32)(t + e * BLK);
        u32 r = lo;
        for (u32 q = lo; q < hi2; q++) r += (skey[q] < me) ? 1u : 0u;
        sidx[r] = (u32)me;  // original column index at sorted rank r
    }
    __syncthreads();

    // ---- gather coords once: thread t owns sorted ranks t*8+e ----
    float X1[EPT], Y1[EPT], X2[EPT], Y2[EPT];
    int OI[EPT];
    u32 amask = 0;
#pragma unroll
    for (int e = 0; e < EPT; e++) {
        int j = (int)sidx[t * EPT + e];
        OI[e] = j;
        float cx = p[j], cy = p[NBOX + j];
        float w = p[2 * NBOX + j], h = p[3 * NBOX + j];
        float s = p[4 * NBOX + j];
        X1[e] = cx - w * 0.5f; Y1[e] = cy - h * 0.5f;
        X2[e] = cx + w * 0.5f; Y2[e] = cy + h * 0.5f;
        if (s > 0.0f) amask |= (1u << e);
    }

    // ---- batched greedy loop ----
    while (true) {
        // block scan of alive counts
        int myAlive = __popc(amask);
        int x = myAlive;
        for (int d = 1; d < 64; d <<= 1) {
            int y = __shfl_up(x, d, 64);
            if (lane >= d) x += y;
        }
        if (lane == 63) wcnt[wid] = x;
        __syncthreads();  // B1: wcnt visible; prev-iter bx4 readers done
        int wb = 0, S = 0;
        for (int i = 0; i < BLK / 64; i++) {
            int v = wcnt[i];
            if (i < wid) wb += v;
            S += v;
        }
        if (S == 0) break;
        int nb = S < 64 ? S : 64;
        int r = wb + x - myAlive;  // my exclusive prefix among alive (sorted order)

        // scatter first-64 alive into batch; remember slots (packed, slot+1 per byte)
        u64 slotpk = 0;
#pragma unroll
        for (int e = 0; e < EPT; e++) {
            if (amask & (1u << e)) {
                if (r < 64) {
                    bx4[r] = make_float4(X1[e], Y1[e], X2[e], Y2[e]);
                    slotpk |= ((u64)(u32)(r + 1)) << (8 * e);
                }
                r++;
            }
        }
        __syncthreads();  // B2: batch visible

        // resolve batch greedily — uniform ctz walk, all waves redundantly
        float4 bb = bx4[lane < nb ? lane : 0];
        float barL = (bb.z - bb.x) * (bb.w - bb.y);
        u64 aliveb = (nb >= 64) ? ~0ull : ((1ull << nb) - 1ull);
        u64 kept = 0;
        while (aliveb) {
            int l = __builtin_ctzll(aliveb);
            kept |= (1ull << l);
            aliveb &= ~(1ull << l);
            float4 cb = bx4[l];
            float car = (cb.z - cb.x) * (cb.w - cb.y);
            float iw = fminf(bb.z, cb.z) - fmaxf(bb.x, cb.x); iw = fmaxf(iw, 0.0f);
            float ih = fminf(bb.w, cb.w) - fmaxf(bb.y, cb.y); ih = fmaxf(ih, 0.0f);
            float inter = iw * ih;
            float uni = car + barL - inter;
            bool sup = (lane < nb) && (lane != l) && (inter / (uni + 1e-8f) >= IOU_THR);
            u64 sm = __ballot(sup);
            aliveb &= ~sm;
        }

        // my batch members: record kept, remove from alive set
#pragma unroll
        for (int e = 0; e < EPT; e++) {
            int se = (int)((slotpk >> (8 * e)) & 0xFFull);
            if (se) {
                se--;
                if ((kept >> se) & 1ull) atomicOr(&kom[OI[e] >> 5], 1u << (OI[e] & 31));
                amask &= ~(1u << e);
            }
        }

        // tail suppression: my remaining alive boxes vs newly-kept batch boxes
        u64 k2 = kept;
        while (k2 && amask) {
            int c = __builtin_ctzll(k2);
            k2 &= k2 - 1;
            float4 cb = bx4[c];
            float car = (cb.z - cb.x) * (cb.w - cb.y);
#pragma unroll
            for (int e = 0; e < EPT; e++) {
                if (amask & (1u << e)) {
                    float iw = fminf(X2[e], cb.z) - fmaxf(X1[e], cb.x); iw = fmaxf(iw, 0.0f);
                    float ih = fminf(Y2[e], cb.w) - fmaxf(Y1[e], cb.y); ih = fmaxf(ih, 0.0f);
                    float inter = iw * ih;
                    float arE = (X2[e] - X1[e]) * (Y2[e] - Y1[e]);
                    float uni = car + arE - inter;
                    if (inter / (uni + 1e-8f) >= IOU_THR) amask &= ~(1u << e);
                }
            }
        }
    }
    __syncthreads();

    // ---- output: 2-level parallel prefix over keep bitmask ----
    {
        u32 w = (t < NBOX / 32) ? kom[t] : 0u;
        int c = __popc(w);
        int x = c;
        for (int d = 1; d < 64; d <<= 1) {
            int y = __shfl_up(x, d, 64);
            if (lane >= d) x += y;
        }
        if (lane == 63) wcnt[wid] = x;
        __syncthreads();
        int wb = 0;
        for (int i = 0; i < wid; i++) wb += wcnt[i];
        if (t < NBOX / 32) pfx[t] = (u32)(wb + x - c);
    }
    __syncthreads();

    // scatter kept columns (d_out pre-zeroed by zero_kernel)
    for (int j = t; j < NBOX; j += BLK) {
        u32 km = kom[j >> 5];
        if ((km >> (j & 31)) & 1u) {
            int pos = (int)(pfx[j >> 5] + (u32)__popc(km & ((1u << (j & 31)) - 1u)));
            o[0 * NBOX + pos] = p[0 * NBOX + j];
            o[1 * NBOX + pos] = p[1 * NBOX + j];
            o[2 * NBOX + pos] = p[2 * NBOX + j];
            o[3 * NBOX + pos] = p[3 * NBOX + j];
            o[4 * NBOX + pos] = p[4 * NBOX + j];
        }
    }
}

extern "C" void kernel_launch(void* const* d_in, const int* in_sizes, int n_in,
                              void* d_out, int out_size, void* d_ws, size_t ws_size,
                              hipStream_t stream) {
    const float* in = (const float*)d_in[0];
    float* out = (float*)d_out;
    int B = in_sizes[0] / (5 * NBOX);
    int n4 = B * 5 * NBOX / 4;
    hipLaunchKernelGGL(zero_kernel, dim3((n4 + 255) / 256), dim3(256), 0, stream,
                       (float4*)out, n4);
    hipLaunchKernelGGL(nms_kernel, dim3(B), dim3(BLK), 0, stream, in, out);
}

// Round 3
// 376.286 us; speedup vs baseline: 1.4579x; 1.4579x over previous
//
#include <hip/hip_runtime.h>

#pragma clang fp contract(off)

#define NBOX 8192
#define BLK  1024
#define EPT  8            // elements per thread (NBOX / BLK)
#define NBUCK 2048
#define IOU_THR 0.1f

typedef unsigned int u32;
typedef unsigned long long u64;

__global__ void zero_kernel(float4* __restrict__ o, int n4) {
    int i = blockIdx.x * blockDim.x + threadIdx.x;
    if (i < n4) { float4 z; z.x = z.y = z.z = z.w = 0.0f; o[i] = z; }
}

__global__ __launch_bounds__(BLK, 4) void nms_kernel(const float* __restrict__ in,
                                                     float* __restrict__ out) {
    const int img = blockIdx.x;
    const float* __restrict__ p = in + (size_t)img * 5 * NBOX;
    float* __restrict__ o = out + (size_t)img * 5 * NBOX;
    const int t = threadIdx.x;
    const int lane = t & 63;
    const int wid = t >> 6;

    __shared__ u64 skey[NBOX];        // 64 KB
    __shared__ u32 sidx[NBOX];        // 32 KB
    __shared__ u32 hist[NBUCK];       // 8 KB
    __shared__ u32 bbase[NBUCK];      // 8 KB
    __shared__ u32 kom[NBOX / 32];    // 1 KB keep bitmask (original idx)
    __shared__ u32 pfx[NBOX / 32];    // 1 KB
    __shared__ float4 bx4[64];        // 1 KB batch boxes (x1,y1,x2,y2)
    __shared__ int wcnt[BLK / 64];
    __shared__ u64 keptSh;

    // ---- init ----
    for (int i = t; i < NBUCK; i += BLK) hist[i] = 0;
    for (int i = t; i < NBOX / 32; i += BLK) kom[i] = 0;
    __syncthreads();

    // ---- pass 1: bucket + arrival order (uniform scores -> ~4/bucket) ----
    u32 mybkt[EPT], myarr[EPT], mykeyhi[EPT];
#pragma unroll
    for (int e = 0; e < EPT; e++) {
        int j = t + e * BLK;
        float s = p[4 * NBOX + j];
        u32 u = __float_as_uint(s);
        u32 ordb = u ^ (u32)(((int)u >> 31) | (int)0x80000000);  // ascending orderable
        mykeyhi[e] = ~ordb;                                      // ascending == score desc
        int vb = (int)(s * (float)NBUCK);
        vb = vb < 0 ? 0 : (vb > NBUCK - 1 ? NBUCK - 1 : vb);
        mybkt[e] = (u32)(NBUCK - 1 - vb);
        myarr[e] = atomicAdd(&hist[mybkt[e]], 1u);
    }
    __syncthreads();

    // ---- exclusive scan over hist (2 bins/thread) ----
    {
        u32 h0 = hist[2 * t], h1 = hist[2 * t + 1];
        int v = (int)(h0 + h1);
        int x = v;
        for (int d = 1; d < 64; d <<= 1) {
            int y = __shfl_up(x, d, 64);
            if (lane >= d) x += y;
        }
        if (lane == 63) wcnt[wid] = x;
        __syncthreads();
        int wb = 0;
        for (int i = 0; i < wid; i++) wb += wcnt[i];
        int excl = wb + x - v;
        bbase[2 * t] = (u32)excl;
        bbase[2 * t + 1] = (u32)excl + h0;
    }
    __syncthreads();

    // ---- scatter keys into bucket regions ----
#pragma unroll
    for (int e = 0; e < EPT; e++) {
        u32 pos = bbase[mybkt[e]] + myarr[e];
        skey[pos] = ((u64)mykeyhi[e] << 32) | (u32)(t + e * BLK);
    }
    __syncthreads();

    // ---- rank within bucket (independent LDS reads, no chains) ----
#pragma unroll
    for (int e = 0; e < EPT; e++) {
        u32 b = mybkt[e];
        u32 lo = bbase[b], hi2 = lo + hist[b];
        u64 me = ((u64)mykeyhi[e] << 32) | (u32)(t + e * BLK);
        u32 r = lo;
        for (u32 q = lo; q < hi2; q++) r += (skey[q] < me) ? 1u : 0u;
        sidx[r] = (u32)me;
    }
    __syncthreads();

    // ---- gather coords once: thread t owns sorted ranks t*8+e ----
    float X1[EPT], Y1[EPT], X2[EPT], Y2[EPT], AR[EPT];
    int OI[EPT];
    u32 amask = 0;
#pragma unroll
    for (int e = 0; e < EPT; e++) {
        int j = (int)sidx[t * EPT + e];
        OI[e] = j;
        float cx = p[j], cy = p[NBOX + j];
        float w = p[2 * NBOX + j], h = p[3 * NBOX + j];
        float s = p[4 * NBOX + j];
        X1[e] = cx - w * 0.5f; Y1[e] = cy - h * 0.5f;
        X2[e] = cx + w * 0.5f; Y2[e] = cy + h * 0.5f;
        AR[e] = (X2[e] - X1[e]) * (Y2[e] - Y1[e]);
        if (s > 0.0f) amask |= (1u << e);
    }

    // ---- batched greedy loop ----
    while (true) {
        // block scan of alive counts
        int myAlive = __popc(amask);
        int x = myAlive;
        for (int d = 1; d < 64; d <<= 1) {
            int y = __shfl_up(x, d, 64);
            if (lane >= d) x += y;
        }
        if (lane == 63) wcnt[wid] = x;
        __syncthreads();  // B1 (also protects bx4/keptSh from prev iter readers)
        int wb = 0, S = 0;
        for (int i = 0; i < BLK / 64; i++) {
            int v = wcnt[i];
            if (i < wid) wb += v;
            S += v;
        }
        if (S == 0) break;
        int nb = S < 64 ? S : 64;
        int r = wb + x - myAlive;

        // scatter first-64 alive into batch; remember slots (slot+1 per byte)
        u64 slotpk = 0;
#pragma unroll
        for (int e = 0; e < EPT; e++) {
            if (amask & (1u << e)) {
                if (r < 64) {
                    bx4[r] = make_float4(X1[e], Y1[e], X2[e], Y2[e]);
                    slotpk |= ((u64)(u32)(r + 1)) << (8 * e);
                }
                r++;
            }
        }
        __syncthreads();  // B2: batch visible

        // wave 0: build 64x64 suppression matrix, resolve via parallel closure
        if (wid == 0) {
            float4 bb = bx4[lane < nb ? lane : 0];
            float barL = (bb.z - bb.x) * (bb.w - bb.y);
            u64 myrow = 0;
            for (int j = 0; j < nb; j++) {
                float4 cb = bx4[j];
                float car = (cb.z - cb.x) * (cb.w - cb.y);
                float iw = fminf(bb.z, cb.z) - fmaxf(bb.x, cb.x);
                float ih = fminf(bb.w, cb.w) - fmaxf(bb.y, cb.y);
                if (iw > 0.0f && ih > 0.0f) {
                    float inter = iw * ih;
                    float uni = car + barL - inter;
                    if (inter / (uni + 1e-8f) >= IOU_THR) myrow |= (1ull << j);
                }
            }
            myrow &= ~(1ull << lane);
            if (lane >= nb) myrow = 0;

            u64 alive0 = (nb >= 64) ? ~0ull : ((1ull << nb) - 1ull);
            u64 keptb = 0;
            u64 below = (1ull << lane) - 1ull;
            while (alive0) {
                bool iscand = ((alive0 >> lane) & 1ull) && ((myrow & alive0 & below) == 0ull);
                u64 cand = __ballot(iscand);
                keptb |= cand;
                alive0 &= ~cand;
                bool supd = ((alive0 >> lane) & 1ull) && ((myrow & cand) != 0ull);
                u64 sup = __ballot(supd);
                alive0 &= ~sup;
            }
            if (lane == 0) keptSh = keptb;
        }
        __syncthreads();  // B3: kept visible

        u64 kept = keptSh;

        // my batch members: record kept, remove from alive set
#pragma unroll
        for (int e = 0; e < EPT; e++) {
            int se = (int)((slotpk >> (8 * e)) & 0xFFull);
            if (se) {
                se--;
                if ((kept >> se) & 1ull) atomicOr(&kom[OI[e] >> 5], 1u << (OI[e] & 31));
                amask &= ~(1u << e);
            }
        }

        // tail suppression vs newly-kept batch boxes
        u64 k2 = kept;
        while (k2 && amask) {
            int c = __builtin_ctzll(k2);
            k2 &= k2 - 1;
            float4 cb = bx4[c];
            float car = (cb.z - cb.x) * (cb.w - cb.y);
#pragma unroll
            for (int e = 0; e < EPT; e++) {
                if (amask & (1u << e)) {
                    float iw = fminf(X2[e], cb.z) - fmaxf(X1[e], cb.x);
                    float ih = fminf(Y2[e], cb.w) - fmaxf(Y1[e], cb.y);
                    if (iw > 0.0f && ih > 0.0f) {
                        float inter = iw * ih;
                        float uni = car + AR[e] - inter;
                        if (inter / (uni + 1e-8f) >= IOU_THR) amask &= ~(1u << e);
                    }
                }
            }
        }
    }
    __syncthreads();

    // ---- output: 2-level parallel prefix over keep bitmask ----
    {
        u32 w = (t < NBOX / 32) ? kom[t] : 0u;
        int c = __popc(w);
        int x = c;
        for (int d = 1; d < 64; d <<= 1) {
            int y = __shfl_up(x, d, 64);
            if (lane >= d) x += y;
        }
        if (lane == 63) wcnt[wid] = x;
        __syncthreads();
        int wb = 0;
        for (int i = 0; i < wid; i++) wb += wcnt[i];
        if (t < NBOX / 32) pfx[t] = (u32)(wb + x - c);
    }
    __syncthreads();

    // scatter kept columns (d_out pre-zeroed by zero_kernel)
    for (int j = t; j < NBOX; j += BLK) {
        u32 km = kom[j >> 5];
        if ((km >> (j & 31)) & 1u) {
            int pos = (int)(pfx[j >> 5] + (u32)__popc(km & ((1u << (j & 31)) - 1u)));
            o[0 * NBOX + pos] = p[0 * NBOX + j];
            o[1 * NBOX + pos] = p[1 * NBOX + j];
            o[2 * NBOX + pos] = p[2 * NBOX + j];
            o[3 * NBOX + pos] = p[3 * NBOX + j];
            o[4 * NBOX + pos] = p[4 * NBOX + j];
        }
    }
}

extern "C" void kernel_launch(void* const* d_in, const int* in_sizes, int n_in,
                              void* d_out, int out_size, void* d_ws, size_t ws_size,
                              hipStream_t stream) {
    const float* in = (const float*)d_in[0];
    float* out = (float*)d_out;
    int B = in_sizes[0] / (5 * NBOX);
    int n4 = B * 5 * NBOX / 4;
    hipLaunchKernelGGL(zero_kernel, dim3((n4 + 255) / 256), dim3(256), 0, stream,
                       (float4*)out, n4);
    hipLaunchKernelGGL(nms_kernel, dim3(B), dim3(BLK), 0, stream, in, out);
}